// Round 1
// baseline (1109.355 us; speedup 1.0000x reference)
//
#include <hip/hip_runtime.h>
#include <math.h>

#define BATCH 1024
#define NSLOT 128
#define DDIM  512
#define BB 8

__device__ __forceinline__ float sigmoidf_(float x) { return 1.0f / (1.0f + expf(-x)); }
__device__ __forceinline__ float clip01(float x) { return fminf(fmaxf(x, 0.0f), 1.0f); }
__device__ __forceinline__ float dot4(float4 a, float4 b) {
    return fmaf(a.x, b.x, fmaf(a.y, b.y, fmaf(a.z, b.z, a.w * b.w)));
}

// Kernel 1: candidate_key = tanh(h@Wk+bk), candidate_value = tanh(h@Wv+bv)
// grid (BATCH/BB, 2), block 256. Each thread owns one output column (half per blockIdx.y).
__global__ __launch_bounds__(256) void k_gemm(
    const float* __restrict__ hidden,
    const float* __restrict__ Wk, const float* __restrict__ bk,
    const float* __restrict__ Wv, const float* __restrict__ bv,
    float* __restrict__ ck, float* __restrict__ cv)
{
    __shared__ float hs[BB][DDIM];
    const int b0 = blockIdx.x * BB;
    const int c = blockIdx.y * 256 + threadIdx.x;
    for (int i = threadIdx.x; i < BB * DDIM; i += 256)
        hs[i / DDIM][i % DDIM] = hidden[(size_t)b0 * DDIM + i];
    __syncthreads();

    float ak[BB], av[BB];
#pragma unroll
    for (int bb = 0; bb < BB; ++bb) { ak[bb] = 0.f; av[bb] = 0.f; }

#pragma unroll 4
    for (int e = 0; e < DDIM; ++e) {
        const float wk = Wk[(size_t)e * DDIM + c];
        const float wv = Wv[(size_t)e * DDIM + c];
#pragma unroll
        for (int bb = 0; bb < BB; ++bb) {
            ak[bb] = fmaf(hs[bb][e], wk, ak[bb]);
            av[bb] = fmaf(hs[bb][e], wv, av[bb]);
        }
    }
    const float bkc = bk[c], bvc = bv[c];
#pragma unroll
    for (int bb = 0; bb < BB; ++bb) {
        ck[(size_t)(b0 + bb) * DDIM + c] = tanhf(ak[bb] + bkc);
        cv[(size_t)(b0 + bb) * DDIM + c] = tanhf(av[bb] + bvc);
    }
}

// Kernel 2: per-b scalar projections of hidden + ||ck|| for normalization.
// grid BATCH, block 64 (one wave).
__global__ __launch_bounds__(64) void k_scal(
    const float* __restrict__ hidden, const float* __restrict__ ck,
    const float* __restrict__ Wwr, const float* __restrict__ bwr,
    const float* __restrict__ Wmg, const float* __restrict__ bmg,
    const float* __restrict__ Wbd, const float* __restrict__ bbd,
    const float* __restrict__ Wim, const float* __restrict__ bim,
    float* __restrict__ scal)
{
    const int b = blockIdx.x;
    const int lane = threadIdx.x;
    const float4* h4 = (const float4*)(hidden + (size_t)b * DDIM);
    const float4* c4 = (const float4*)(ck + (size_t)b * DDIM);
    const float4* wr4 = (const float4*)Wwr;
    const float4* mg4 = (const float4*)Wmg;
    const float4* bd4 = (const float4*)Wbd;
    const float4* im4 = (const float4*)Wim;

    float dwr = 0.f, dmg = 0.f, dbd = 0.f, dim = 0.f, css = 0.f;
#pragma unroll
    for (int i = 0; i < 2; ++i) {
        const int idx = lane + i * 64;  // 0..127 float4 = 512 floats
        const float4 h = h4[idx];
        const float4 c = c4[idx];
        dwr += dot4(h, wr4[idx]);
        dmg += dot4(h, mg4[idx]);
        dbd += dot4(h, bd4[idx]);
        dim += dot4(h, im4[idx]);
        css += dot4(c, c);
    }
#pragma unroll
    for (int off = 32; off > 0; off >>= 1) {
        dwr += __shfl_down(dwr, off, 64);
        dmg += __shfl_down(dmg, off, 64);
        dbd += __shfl_down(dbd, off, 64);
        dim += __shfl_down(dim, off, 64);
        css += __shfl_down(css, off, 64);
    }
    if (lane == 0) {
        scal[b * 5 + 0] = sigmoidf_(dwr + bwr[0]);              // write_strength
        scal[b * 5 + 1] = sigmoidf_(dim + bim[0]);              // importance
        scal[b * 5 + 2] = dmg + bmg[0];                         // merge logit part
        scal[b * 5 + 3] = dbd + bbd[0];                         // bind logit part
        scal[b * 5 + 4] = 1.0f / fmaxf(sqrtf(css), 1e-6f);      // 1/max(||ck||,eps)
    }
}

// Kernel 3: THE streaming pass. One wave per (b,n) row.
// Reads keys+values rows once, computes 5 reductions, copies rows to outputs.
__global__ __launch_bounds__(256) void k_stream(
    const float* __restrict__ wkeys, const float* __restrict__ wvals,
    const float* __restrict__ wprot,
    const float* __restrict__ ck, const float* __restrict__ scal,
    const float* __restrict__ Woc, const float* __restrict__ boc,
    const float* __restrict__ Wpr, const float* __restrict__ bpr,
    float* __restrict__ out_keys, float* __restrict__ out_vals,
    float* __restrict__ sim_ws, float* __restrict__ occ_ws, float* __restrict__ epr_ws)
{
    const int wave = threadIdx.x >> 6;
    const int lane = threadIdx.x & 63;
    const size_t r = (size_t)blockIdx.x * 4 + wave;          // row index < BATCH*NSLOT
    const int b = (int)(r >> 7);
    const float4* k4 = (const float4*)wkeys + r * (DDIM / 4);
    const float4* v4 = (const float4*)wvals + r * (DDIM / 4);
    const float4* c4 = (const float4*)ck + (size_t)b * (DDIM / 4);
    const float4* oc4 = (const float4*)Woc;
    const float4* pr4 = (const float4*)Wpr;
    float4* ok4 = (float4*)out_keys + r * (DDIM / 4);
    float4* ov4 = (float4*)out_vals + r * (DDIM / 4);

    float dk = 0.f, kk = 0.f, vv = 0.f, doc = 0.f, dpr = 0.f;
#pragma unroll
    for (int i = 0; i < 2; ++i) {
        const int idx = lane + i * 64;                       // coalesced float4 per wave
        const float4 k = k4[idx];
        const float4 c = c4[idx];
        const float4 v = v4[idx];
        dk  += dot4(k, c);
        kk  += dot4(k, k);
        vv  += dot4(v, v);
        doc += dot4(v, oc4[idx]);
        dpr += dot4(v, pr4[idx]);
        ok4[idx] = k;                                        // fused copy
        ov4[idx] = v;
    }
#pragma unroll
    for (int off = 32; off > 0; off >>= 1) {
        dk  += __shfl_down(dk, off, 64);
        kk  += __shfl_down(kk, off, 64);
        vv  += __shfl_down(vv, off, 64);
        doc += __shfl_down(doc, off, 64);
        dpr += __shfl_down(dpr, off, 64);
    }
    if (lane == 0) {
        const float inv_ck = scal[b * 5 + 4];
        const float sim = dk * inv_ck * (1.0f / fmaxf(sqrtf(kk), 1e-6f));
        const float nocc = clip01(sqrtf(vv) * 0.04419417382415922f);  // 1/sqrt(512)
        const float locc = sigmoidf_(doc + boc[0]);
        const float occ = clip01(0.5f * locc + 0.5f * nocc);
        const float lpr = sigmoidf_(dpr + bpr[0]);
        const float epr = clip01(0.4f * lpr + 0.6f * wprot[r]);
        sim_ws[r] = sim;
        occ_ws[r] = occ;
        epr_ws[r] = epr;
    }
}

// Kernel 4: per-b reductions, gating, scalar outputs, protection, overwrite,
// and the single-target-row fixup of keys/values. grid BATCH, block NSLOT.
__global__ __launch_bounds__(128) void k_final(
    const float* __restrict__ wkeys, const float* __restrict__ wvals,
    const float* __restrict__ wprot, const float* __restrict__ wusage,
    const float* __restrict__ wage,
    const float* __restrict__ ck, const float* __restrict__ cv,
    const float* __restrict__ sim_ws, const float* __restrict__ occ_ws,
    const float* __restrict__ epr_ws, const float* __restrict__ scal,
    float* __restrict__ out_keys, float* __restrict__ out_vals,
    float* __restrict__ out_prot, float* __restrict__ out_wstr,
    float* __restrict__ out_mpref, float* __restrict__ out_bstr,
    float* __restrict__ out_ovmean, float* __restrict__ out_pmean,
    float* __restrict__ out_msim, float* __restrict__ out_ovr)
{
    const int b = blockIdx.x;
    const int n = threadIdx.x;
    __shared__ float s_sim[NSLOT], s_rs[NSLOT], s_occ[NSLOT], s_eu[NSLOT],
                     s_ea[NSLOT], s_ep[NSLOT], s_up[NSLOT];
    __shared__ int s_idx[2];

    const size_t r = (size_t)b * NSLOT + n;
    const float sim = sim_ws[r];
    const float occ = occ_ws[r];
    const float ep  = epr_ws[r];
    const float eu  = clip01(0.5f * occ + 0.5f * wusage[r]);
    const float ea  = clip01(wage[r]);
    const float rs  = 1.15f * (1.f - occ) + 0.85f * (1.f - ep) + 0.65f * ea
                    + 0.45f * (1.f - eu) + 0.25f * (1.f - sim);
    s_sim[n] = sim; s_rs[n] = rs; s_occ[n] = occ;
    s_eu[n] = eu;   s_ea[n] = ea; s_ep[n] = ep;
    __syncthreads();

    if (n == 0) {  // first-index argmax, matching jnp.argmax tie-break
        int mi = 0, ri = 0;
        float mv = s_sim[0], rv = s_rs[0];
        for (int i = 1; i < NSLOT; ++i) {
            if (s_sim[i] > mv) { mv = s_sim[i]; mi = i; }
            if (s_rs[i]  > rv) { rv = s_rs[i];  ri = i; }
        }
        s_idx[0] = mi; s_idx[1] = ri;
    }
    __syncthreads();

    const int mi = s_idx[0], ri = s_idx[1];
    const float max_sim = s_sim[mi];
    const float m_occ = s_occ[mi], m_eu = s_eu[mi], m_ea = s_ea[mi];
    const float wstr = scal[b * 5 + 0];
    const float imv  = scal[b * 5 + 1];
    const float mgl  = scal[b * 5 + 2];
    const float bdl  = scal[b * 5 + 3];

    const float mpref = sigmoidf_(mgl + 2.4f * max_sim + 1.6f * (m_occ - 0.5f)
                                  + 1.0f * (m_eu - 0.5f) - 0.8f * m_ea);
    const bool mcand = (max_sim > 0.55f) && (m_occ > 0.35f);
    const bool use_merge = (mpref >= 0.5f) && mcand;
    const int target = use_merge ? mi : ri;
    const float bstr = sigmoidf_(bdl + 2.2f * max_sim);

    const float conflict_t = clip01(1.f - s_sim[target]);
    const float ov = (0.15f + 0.85f * wstr) * (1.f - 0.65f * s_ep[target] * conflict_t);
    const float ovn = (n == target) ? ov : 0.f;
    out_ovr[r] = ovn;

    const float pb = ovn * (0.5f + 0.5f * imv);
    const float up = clip01(wprot[r] * 0.98f + pb);
    out_prot[r] = up;
    s_up[n] = up;
    __syncthreads();

    if (n == 0) {
        float s = 0.f;
        for (int i = 0; i < NSLOT; ++i) s += s_up[i];
        out_wstr[b]   = wstr;
        out_mpref[b]  = mpref;
        out_bstr[b]   = bstr;
        out_ovmean[b] = ov * (1.0f / NSLOT);
        out_pmean[b]  = s * (1.0f / NSLOT);
        out_msim[b]   = max_sim;
    }

    // Fixup the single target row of keys/values (128 threads x one float4 each).
    const float kmix = use_merge ? (0.22f + 0.38f * bstr) : (0.78f + 0.18f * bstr);
    const float vmix = use_merge ? (0.45f + 0.35f * imv)  : (0.75f + 0.20f * imv);
    const float fk = ov * kmix;
    const float fv = ov * vmix;
    const size_t base = ((size_t)b * NSLOT + target) * DDIM;
    const float4* wk4 = (const float4*)(wkeys + base);
    const float4* wv4 = (const float4*)(wvals + base);
    const float4* ck4 = (const float4*)(ck + (size_t)b * DDIM);
    const float4* cv4 = (const float4*)(cv + (size_t)b * DDIM);
    float4* ok4 = (float4*)(out_keys + base);
    float4* ov4 = (float4*)(out_vals + base);

    const float4 k = wk4[n], c = ck4[n];
    const float4 v = wv4[n], w = cv4[n];
    float4 nk, nv;
    nk.x = fmaf(fk, c.x - k.x, k.x); nk.y = fmaf(fk, c.y - k.y, k.y);
    nk.z = fmaf(fk, c.z - k.z, k.z); nk.w = fmaf(fk, c.w - k.w, k.w);
    nv.x = fmaf(fv, w.x - v.x, v.x); nv.y = fmaf(fv, w.y - v.y, v.y);
    nv.z = fmaf(fv, w.z - v.z, v.z); nv.w = fmaf(fv, w.w - v.w, v.w);
    ok4[n] = nk;
    ov4[n] = nv;
}

extern "C" void kernel_launch(void* const* d_in, const int* in_sizes, int n_in,
                              void* d_out, int out_size, void* d_ws, size_t ws_size,
                              hipStream_t stream)
{
    (void)in_sizes; (void)n_in; (void)out_size; (void)ws_size;

    const float* hidden = (const float*)d_in[0];
    const float* wkeys  = (const float*)d_in[1];
    const float* wvals  = (const float*)d_in[2];
    const float* wprot  = (const float*)d_in[3];
    const float* wusage = (const float*)d_in[4];
    const float* wage   = (const float*)d_in[5];
    const float* Wk  = (const float*)d_in[6];
    const float* bk  = (const float*)d_in[7];
    const float* Wv  = (const float*)d_in[8];
    const float* bv  = (const float*)d_in[9];
    const float* Wwr = (const float*)d_in[10];
    const float* bwr = (const float*)d_in[11];
    const float* Wmg = (const float*)d_in[12];
    const float* bmg = (const float*)d_in[13];
    const float* Wbd = (const float*)d_in[14];
    const float* bbd = (const float*)d_in[15];
    const float* Wim = (const float*)d_in[16];
    const float* bim = (const float*)d_in[17];
    const float* Woc = (const float*)d_in[18];
    const float* boc = (const float*)d_in[19];
    const float* Wpr = (const float*)d_in[20];
    const float* bpr = (const float*)d_in[21];

    float* out = (float*)d_out;
    const size_t BND = (size_t)BATCH * NSLOT * DDIM;   // 67,108,864
    const size_t BN  = (size_t)BATCH * NSLOT;          // 131,072
    float* out_keys   = out;
    float* out_vals   = out_keys + BND;
    float* out_prot   = out_vals + BND;
    float* out_wstr   = out_prot + BN;
    float* out_mpref  = out_wstr + BATCH;
    float* out_bstr   = out_mpref + BATCH;
    float* out_ovmean = out_bstr + BATCH;
    float* out_pmean  = out_ovmean + BATCH;
    float* out_msim   = out_pmean + BATCH;
    float* out_ovr    = out_msim + BATCH;

    float* ws  = (float*)d_ws;
    float* ck  = ws;                                   // B*D
    float* cv  = ck + (size_t)BATCH * DDIM;            // B*D
    float* simw = cv + (size_t)BATCH * DDIM;           // B*N
    float* occw = simw + BN;                           // B*N
    float* eprw = occw + BN;                           // B*N
    float* scal = eprw + BN;                           // B*5

    k_gemm<<<dim3(BATCH / BB, 2), 256, 0, stream>>>(hidden, Wk, bk, Wv, bv, ck, cv);
    k_scal<<<BATCH, 64, 0, stream>>>(hidden, ck, Wwr, bwr, Wmg, bmg, Wbd, bbd,
                                     Wim, bim, scal);
    k_stream<<<(BATCH * NSLOT) / 4, 256, 0, stream>>>(
        wkeys, wvals, wprot, ck, scal, Woc, boc, Wpr, bpr,
        out_keys, out_vals, simw, occw, eprw);
    k_final<<<BATCH, NSLOT, 0, stream>>>(
        wkeys, wvals, wprot, wusage, wage, ck, cv, simw, occw, eprw, scal,
        out_keys, out_vals, out_prot, out_wstr, out_mpref, out_bstr,
        out_ovmean, out_pmean, out_msim, out_ovr);
}